// Round 3
// baseline (412.344 us; speedup 1.0000x reference)
//
#include <hip/hip_runtime.h>

// result = sum_i | sum_j flow[i,j] - sum_j flow[j,i] |, N=8192 fp32.
// R3: hot loop is pure loads+register adds (no shuffles, no atomics).
//   pass1: grid (4 col-quarters, 128 row-strips); each block 64 rows x 512 f4.
//     - per-lane row partial -> LDS (ds_write_b32), block row-reduce -> rowpart
//     - register colacc -> LDS cross-wave reduce -> colpart
//     both written as plain coalesced stores into d_ws (no poison dependence:
//     every slot read by pass2 is written by pass1).
//   pass2: 32 blocks; per-column diff = rowsum - colsum, abs, block reduce,
//     one atomicAdd per block into d_out[0] (zeroed by pass1 block (0,0)).

constexpr int N = 8192;
constexpr int N4 = N / 4;         // 2048 float4 per row
constexpr int CQ4 = 512;          // float4 columns per block (quarter)
constexpr int ROWS = 64;          // rows per block
constexpr int RPW = 16;           // rows per wave
constexpr int STRIPS = N / ROWS;  // 128 row strips

// d_ws layout: rowpart[4][N] floats (128 KB) @ 0; colpart[STRIPS][N] floats (4 MB) after.

__global__ __launch_bounds__(256, 2) void pass1_kernel(
    const float* __restrict__ flow, float* __restrict__ rowpart,
    float* __restrict__ colpart, float* __restrict__ out) {
  if (blockIdx.x == 0 && blockIdx.y == 0 && threadIdx.x == 0) out[0] = 0.f;

  const int wave = threadIdx.x >> 6;
  const int lane = threadIdx.x & 63;
  const int bx = blockIdx.x, by = blockIdx.y;
  const int c4base = bx * CQ4;
  const int row0 = by * ROWS + wave * RPW;

  __shared__ float rowbuf[ROWS * 65];   // 16.6 KB, pad 65 -> conflict-free
  __shared__ float4 colbuf[4 * CQ4];    // 32 KB

  const float4* __restrict__ flow4 = reinterpret_cast<const float4*>(flow);

  float4 colacc[8];
#pragma unroll
  for (int j = 0; j < 8; ++j) colacc[j] = make_float4(0.f, 0.f, 0.f, 0.f);

#pragma unroll
  for (int i = 0; i < RPW; ++i) {
    const int r = row0 + i;
    const float4* __restrict__ p = flow4 + (size_t)r * N4 + c4base + lane;
    float4 v[8];
#pragma unroll
    for (int j = 0; j < 8; ++j) v[j] = p[j * 64];  // 8 independent 1KB/wave loads
    float rs = 0.f;
#pragma unroll
    for (int j = 0; j < 8; ++j) {
      colacc[j].x += v[j].x; colacc[j].y += v[j].y;
      colacc[j].z += v[j].z; colacc[j].w += v[j].w;
      rs += (v[j].x + v[j].y) + (v[j].z + v[j].w);
    }
    rowbuf[(wave * RPW + i) * 65 + lane] = rs;  // per-lane row partial, no shuffle
  }
  __syncthreads();

  // block row-reduce: thread t sums 64 lane-partials of row t (banks (t+l)%32, free)
  if (threadIdx.x < ROWS) {
    float s = 0.f;
#pragma unroll 8
    for (int l = 0; l < 64; ++l) s += rowbuf[threadIdx.x * 65 + l];
    rowpart[(size_t)bx * N + by * ROWS + threadIdx.x] = s;
  }

  // cross-wave column reduce -> plain coalesced store of block partial
#pragma unroll
  for (int j = 0; j < 8; ++j) colbuf[wave * CQ4 + j * 64 + lane] = colacc[j];
  __syncthreads();
  float4* __restrict__ colpart4 =
      reinterpret_cast<float4*>(colpart + (size_t)by * N);
  for (int p = threadIdx.x; p < CQ4; p += 256) {
    float4 a = colbuf[p], b = colbuf[CQ4 + p], c = colbuf[2 * CQ4 + p],
           d = colbuf[3 * CQ4 + p];
    float4 s;
    s.x = (a.x + b.x) + (c.x + d.x);
    s.y = (a.y + b.y) + (c.y + d.y);
    s.z = (a.z + b.z) + (c.z + d.z);
    s.w = (a.w + b.w) + (c.w + d.w);
    colpart4[c4base + p] = s;
  }
}

__global__ __launch_bounds__(256) void pass2_kernel(
    const float* __restrict__ rowpart, const float* __restrict__ colpart,
    float* __restrict__ out) {
  const int c = blockIdx.x * 256 + threadIdx.x;  // one column per thread
  float rowsum = (rowpart[c] + rowpart[N + c]) +
                 (rowpart[2 * N + c] + rowpart[3 * N + c]);
  float cs0 = 0.f, cs1 = 0.f, cs2 = 0.f, cs3 = 0.f;
  for (int s = 0; s < STRIPS; s += 4) {  // 4 independent chains, coalesced
    cs0 += colpart[(size_t)(s + 0) * N + c];
    cs1 += colpart[(size_t)(s + 1) * N + c];
    cs2 += colpart[(size_t)(s + 2) * N + c];
    cs3 += colpart[(size_t)(s + 3) * N + c];
  }
  float v = fabsf(rowsum - ((cs0 + cs1) + (cs2 + cs3)));

#pragma unroll
  for (int off = 32; off > 0; off >>= 1) v += __shfl_down(v, off, 64);
  __shared__ float wsum[4];
  if ((threadIdx.x & 63) == 0) wsum[threadIdx.x >> 6] = v;
  __syncthreads();
  if (threadIdx.x == 0)
    atomicAdd(out, (wsum[0] + wsum[1]) + (wsum[2] + wsum[3]));
}

extern "C" void kernel_launch(void* const* d_in, const int* in_sizes, int n_in,
                              void* d_out, int out_size, void* d_ws, size_t ws_size,
                              hipStream_t stream) {
  const float* flow = (const float*)d_in[0];
  float* out = (float*)d_out;
  float* rowpart = (float*)d_ws;                  // 4*N floats = 128 KB
  float* colpart = rowpart + 4 * N;               // STRIPS*N floats = 4 MB

  dim3 grid1(4, STRIPS);  // 512 blocks
  pass1_kernel<<<grid1, 256, 0, stream>>>(flow, rowpart, colpart, out);
  pass2_kernel<<<N / 256, 256, 0, stream>>>(rowpart, colpart, out);
}

// Round 4
// 348.493 us; speedup vs baseline: 1.1832x; 1.1832x over previous
//
#include <hip/hip_runtime.h>

// result = sum_i | sum_j flow[i,j] - sum_j flow[j,i] |, N=8192 fp32.
// R4: R1's high-parallelism grid (4096 blocks) + R3's clean hot loop.
//   pass1: block = 64 rows x 64 float4 (64 KB of data). Hot loop per thread:
//     16 coalesced float4 loads, register col-accumulate, one ds_write_b32
//     row-partial per load. No shuffles, no atomics in the loop.
//     Epilogue: wave0 reduces 64 rows from LDS, wave1 reduces 64 f4-cols —
//     concurrently — then atomicAdd into diff[] (L2-resident, 8192 words).
//   pass2: abs-sum of diff -> d_out[0].

constexpr int N = 8192;
constexpr int N4 = N / 4;  // 2048 float4 per row

__global__ __launch_bounds__(256) void pass1_kernel(
    const float* __restrict__ flow, float* __restrict__ diff) {
  const int wave = threadIdx.x >> 6;
  const int lane = threadIdx.x & 63;
  const int c4 = blockIdx.x * 64 + lane;        // this thread's float4 column
  const int row0 = blockIdx.y * 64 + wave * 16; // 16 consecutive rows per wave

  __shared__ float rowbuf[64 * 65];   // 16.6 KB, +1 pad -> conflict-free
  __shared__ float4 colbuf[4 * 64];   // 4 KB

  const float4* __restrict__ flow4 = reinterpret_cast<const float4*>(flow);

  float4 ca = make_float4(0.f, 0.f, 0.f, 0.f);
#pragma unroll
  for (int i = 0; i < 16; ++i) {
    float4 v = flow4[(size_t)(row0 + i) * N4 + c4];  // 1 KB/wave, coalesced
    ca.x += v.x; ca.y += v.y; ca.z += v.z; ca.w += v.w;
    rowbuf[(wave * 16 + i) * 65 + lane] = (v.x + v.y) + (v.z + v.w);
  }
  colbuf[wave * 64 + lane] = ca;
  __syncthreads();

  if (threadIdx.x < 64) {
    // wave 0: row reduce. thread t sums 64 lane-partials of row t.
    // addresses t*65+l: t vs t+32 -> 2-way bank alias (free).
    float s = 0.f;
#pragma unroll 8
    for (int l = 0; l < 64; ++l) s += rowbuf[threadIdx.x * 65 + l];
    atomicAdd(&diff[blockIdx.y * 64 + threadIdx.x], s);
  } else if (threadIdx.x < 128) {
    // wave 1 (runs concurrently with wave 0): column reduce.
    const int l = threadIdx.x - 64;
    float4 a = colbuf[l], b = colbuf[64 + l], c = colbuf[128 + l],
           d = colbuf[192 + l];
    const int col = (blockIdx.x * 64 + l) * 4;
    atomicAdd(&diff[col + 0], -((a.x + b.x) + (c.x + d.x)));
    atomicAdd(&diff[col + 1], -((a.y + b.y) + (c.y + d.y)));
    atomicAdd(&diff[col + 2], -((a.z + b.z) + (c.z + d.z)));
    atomicAdd(&diff[col + 3], -((a.w + b.w) + (c.w + d.w)));
  }
}

__global__ __launch_bounds__(1024) void abs_reduce_kernel(
    const float* __restrict__ diff, float* __restrict__ out) {
  const float4* __restrict__ d4 = reinterpret_cast<const float4*>(diff);
  float s = 0.f;
#pragma unroll
  for (int i = threadIdx.x; i < N / 4; i += 1024) {
    float4 v = d4[i];
    s += (fabsf(v.x) + fabsf(v.y)) + (fabsf(v.z) + fabsf(v.w));
  }
#pragma unroll
  for (int off = 32; off > 0; off >>= 1) s += __shfl_down(s, off, 64);

  __shared__ float wsum[16];
  if ((threadIdx.x & 63) == 0) wsum[threadIdx.x >> 6] = s;
  __syncthreads();
  if (threadIdx.x < 64) {
    float t = (threadIdx.x < 16) ? wsum[threadIdx.x] : 0.f;
#pragma unroll
    for (int off = 8; off > 0; off >>= 1) t += __shfl_down(t, off, 64);
    if (threadIdx.x == 0) out[0] = t;
  }
}

extern "C" void kernel_launch(void* const* d_in, const int* in_sizes, int n_in,
                              void* d_out, int out_size, void* d_ws, size_t ws_size,
                              hipStream_t stream) {
  const float* flow = (const float*)d_in[0];
  float* out = (float*)d_out;
  float* diff = (float*)d_ws;  // N floats = 32 KB

  hipMemsetAsync(diff, 0, (size_t)N * sizeof(float), stream);

  dim3 grid(N / 256, N / 64);  // (32, 128) = 4096 blocks, ~8 resident/CU
  pass1_kernel<<<grid, 256, 0, stream>>>(flow, diff);
  abs_reduce_kernel<<<1, 1024, 0, stream>>>(diff, out);
}